// Round 2
// baseline (628.790 us; speedup 1.0000x reference)
//
#include <hip/hip_runtime.h>
#include <cmath>

#define B 256
#define N0 512
#define F0 128
#define H 32
#define NC 16

typedef short v8s __attribute__((ext_vector_type(8)));
typedef float v4f __attribute__((ext_vector_type(4)));
typedef unsigned short v8u __attribute__((ext_vector_type(8)));

__device__ inline ushort bf16_rne(float f) {
  unsigned u = __float_as_uint(f);
  unsigned r = (u + 0x7FFF + ((u >> 16) & 1)) >> 16;
  return (ushort)r;
}
__device__ inline float bf16_f(ushort s) { return __uint_as_float((unsigned)s << 16); }

// ---------------- Layer-1: x@w1 -> hT (bf16 split, transposed, fused); x@w2+b -> g ----------------
template<int F, int RPT>
__global__ __launch_bounds__(256) void k_xw1(
    const float* __restrict__ x, const float* __restrict__ w1,
    const float* __restrict__ w2, const float* __restrict__ bias,
    ushort* __restrict__ hTh, ushort* __restrict__ hTl, float* __restrict__ g) {
  __shared__ float w1t[H][F + 4];
  __shared__ float w2t[H][F + 4];
  __shared__ float bs[H];
  __shared__ __align__(16) ushort thi[H][72];
  __shared__ __align__(16) ushort tlo[H][72];
  const int tid = threadIdx.x;
  for (int i = tid; i < F * H; i += 256) {
    int f = i >> 5, hc = i & 31;
    w1t[hc][f] = w1[i];
    w2t[hc][f] = w2[i];
  }
  if (tid < H) bs[tid] = bias[tid];
  __syncthreads();
  const int hq = tid & 7;
  const int rq = tid >> 3;
  const size_t row0 = (size_t)blockIdx.x * (32 * RPT) + (size_t)rq * RPT;
  const float* xb = x + row0 * F;
  float acc1[RPT][4];
  float acc2[RPT][4];
  #pragma unroll
  for (int r = 0; r < RPT; ++r)
    for (int c = 0; c < 4; ++c) { acc1[r][c] = 0.f; acc2[r][c] = 0.f; }
  for (int f0 = 0; f0 < F; f0 += 4) {
    float4 w1v[4], w2v[4];
    #pragma unroll
    for (int hh = 0; hh < 4; ++hh) {
      w1v[hh] = *(const float4*)&w1t[hq * 4 + hh][f0];
      w2v[hh] = *(const float4*)&w2t[hq * 4 + hh][f0];
    }
    #pragma unroll
    for (int r = 0; r < RPT; ++r) {
      float4 xv = *(const float4*)(xb + (size_t)r * F + f0);
      #pragma unroll
      for (int hh = 0; hh < 4; ++hh) {
        acc1[r][hh] += xv.x * w1v[hh].x + xv.y * w1v[hh].y + xv.z * w1v[hh].z + xv.w * w1v[hh].w;
        acc2[r][hh] += xv.x * w2v[hh].x + xv.y * w2v[hh].y + xv.z * w2v[hh].z + xv.w * w2v[hh].w;
      }
    }
  }
  #pragma unroll
  for (int r = 0; r < RPT; ++r) {
    size_t o = (row0 + r) * H + hq * 4;
    *(float4*)(g + o) = make_float4(acc2[r][0] + bs[hq * 4 + 0], acc2[r][1] + bs[hq * 4 + 1],
                                    acc2[r][2] + bs[hq * 4 + 2], acc2[r][3] + bs[hq * 4 + 3]);
    #pragma unroll
    for (int c = 0; c < 4; ++c) {
      float v = acc1[r][c];
      ushort hi = bf16_rne(v);
      thi[hq * 4 + c][rq * RPT + r] = hi;
      tlo[hq * 4 + c][rq * RPT + r] = bf16_rne(v - bf16_f(hi));
    }
  }
  __syncthreads();
  const int b = blockIdx.x >> 3;
  const int j0 = (blockIdx.x & 7) * 64;
  const int hrow = tid >> 3, seg = tid & 7;
  size_t o = ((size_t)b * H + hrow) * N0 + j0 + seg * 8;
  *(uint4*)&hTh[o] = *(const uint4*)&thi[hrow][seg * 8];
  *(uint4*)&hTl[o] = *(const uint4*)&tlo[hrow][seg * 8];
}

// ------- Layers 2/3 fused: gather+gate x@w1/@w2 -> g (global) + hT (transposed split, dense) -------
// One block per graph: computes all K kept rows, stages gated h in LDS, emits hT directly.
template<int NPREV, int K>
__global__ __launch_bounds__(256) void k_xwg2(
    const float* __restrict__ xsrc, const int* __restrict__ lidx,
    const float* __restrict__ gate, const int* __restrict__ gidx,
    const float* __restrict__ w1, const float* __restrict__ w2,
    const float* __restrict__ bias,
    float* __restrict__ g, ushort* __restrict__ hTh, ushort* __restrict__ hTl) {
  constexpr int F = H;
  constexpr int RPT = K / 32;
  __shared__ float w1t[H][F + 4];
  __shared__ float w2t[H][F + 4];
  __shared__ float bs[H];
  __shared__ float hs[K][36];           // 36: keeps float4 row stores 16B-aligned
  __shared__ int inv[N0];
  const int tid = threadIdx.x;
  const int b = blockIdx.x;
  for (int i = tid; i < F * H; i += 256) {
    int f = i >> 5, hc = i & 31;
    w1t[hc][f] = w1[i];
    w2t[hc][f] = w2[i];
  }
  if (tid < H) bs[tid] = bias[tid];
  for (int j = tid; j < N0; j += 256) inv[j] = -1;
  __syncthreads();
  for (int k = tid; k < K; k += 256) inv[gidx[(size_t)b * K + k]] = k;
  const int hq = tid & 7;
  const int rq = tid >> 3;
  const int r0 = rq * RPT;
  const float* xg0 = xsrc + (size_t)b * NPREV * H;
  int li[RPT];
  float gt[RPT];
  #pragma unroll
  for (int r = 0; r < RPT; ++r) {
    li[r] = lidx[(size_t)b * K + r0 + r];
    gt[r] = gate[(size_t)b * K + r0 + r];
  }
  float acc1[RPT][4];
  float acc2[RPT][4];
  #pragma unroll
  for (int r = 0; r < RPT; ++r)
    for (int c = 0; c < 4; ++c) { acc1[r][c] = 0.f; acc2[r][c] = 0.f; }
  for (int f0 = 0; f0 < F; f0 += 4) {
    float4 w1v[4], w2v[4];
    #pragma unroll
    for (int hh = 0; hh < 4; ++hh) {
      w1v[hh] = *(const float4*)&w1t[hq * 4 + hh][f0];
      w2v[hh] = *(const float4*)&w2t[hq * 4 + hh][f0];
    }
    #pragma unroll
    for (int r = 0; r < RPT; ++r) {
      float4 xv = *(const float4*)(xg0 + (size_t)li[r] * H + f0);
      #pragma unroll
      for (int hh = 0; hh < 4; ++hh) {
        acc1[r][hh] += xv.x * w1v[hh].x + xv.y * w1v[hh].y + xv.z * w1v[hh].z + xv.w * w1v[hh].w;
        acc2[r][hh] += xv.x * w2v[hh].x + xv.y * w2v[hh].y + xv.z * w2v[hh].z + xv.w * w2v[hh].w;
      }
    }
  }
  #pragma unroll
  for (int r = 0; r < RPT; ++r) {
    size_t o = ((size_t)b * K + r0 + r) * H + hq * 4;
    *(float4*)(g + o) = make_float4(acc2[r][0] * gt[r] + bs[hq * 4 + 0],
                                    acc2[r][1] * gt[r] + bs[hq * 4 + 1],
                                    acc2[r][2] * gt[r] + bs[hq * 4 + 2],
                                    acc2[r][3] * gt[r] + bs[hq * 4 + 3]);
    *(float4*)&hs[r0 + r][hq * 4] = make_float4(acc1[r][0] * gt[r], acc1[r][1] * gt[r],
                                                acc1[r][2] * gt[r], acc1[r][3] * gt[r]);
  }
  __syncthreads();
  for (int t = tid; t < H * 64; t += 256) {
    int hr = t >> 6, seg = t & 63;
    v8u hv, lv;
    #pragma unroll
    for (int i = 0; i < 8; ++i) {
      int kk = inv[seg * 8 + i];
      float v = (kk >= 0) ? hs[kk][hr] : 0.f;
      ushort hi = bf16_rne(v);
      hv[i] = hi;
      lv[i] = bf16_rne(v - bf16_f(hi));
    }
    size_t o = ((size_t)b * H + hr) * N0 + seg * 8;
    *(v8u*)&hTh[o] = hv;
    *(v8u*)&hTl[o] = lv;
  }
}

// ---------------- MFMA amm: out = relu(A[rid,:] @ h + g), split-bf16, K=512 ----------------
// KC=64, register double-buffered A/B prefetch (loads for chunk c+1 in flight across
// convert + barriers + MFMAs of chunk c). 8 chunks, fully unrolled -> static dbuf indices.
template<int NROW>
__global__ __launch_bounds__(256) void k_ammx(
    const float* __restrict__ a0, const int* __restrict__ rid,
    const ushort* __restrict__ hTh, const ushort* __restrict__ hTl,
    const float* __restrict__ g, const float* __restrict__ p,
    float* __restrict__ out, float* __restrict__ yout) {
  constexpr int RB = 64;
  constexpr int KC = 64;
  constexpr int NCH = N0 / KC;   // 8
  constexpr int ASP = KC + 8;    // 72: 144B rows keep b128 frag reads 16B-aligned
  __shared__ ushort ah[RB][ASP];
  __shared__ ushort al[RB][ASP];
  __shared__ ushort bh[H][ASP];
  __shared__ ushort bl[H][ASP];
  __shared__ int rowid[RB];
  __shared__ float psu[H];
  __shared__ float pns_s;
  const int tid = threadIdx.x;
  const int b = blockIdx.x;
  const int row0 = blockIdx.y * RB;
  if (tid < RB) rowid[tid] = rid ? rid[(size_t)b * NROW + row0 + tid] : row0 + tid;
  if (yout && tid == 0) {
    float s = 0.f;
    for (int i = 0; i < H; ++i) s += p[i] * p[i];
    pns_s = 1.f / sqrtf(s);
  }
  __syncthreads();
  if (yout && tid < H) psu[tid] = p[tid] * pns_s;  // ordered by in-loop barriers
  const int wave = tid >> 6, lane = tid & 63;
  const int m = lane & 15, quad = lane >> 4;
  const int sr = tid >> 2, skq = tid & 3;     // A staging: row, col-group (4x16 floats)
  const int shh = tid >> 3, sseg = tid & 7;   // B staging: h-row, 8-col seg
  const float* ap = a0 + (size_t)b * N0 * N0 + (size_t)rowid[sr] * N0 + skq * 4;
  const ushort* bhsrc = hTh + ((size_t)b * H + shh) * N0 + sseg * 8;
  const ushort* blsrc = hTl + ((size_t)b * H + shh) * N0 + sseg * 8;
  v4f acc0 = {0.f, 0.f, 0.f, 0.f};
  v4f acc1 = {0.f, 0.f, 0.f, 0.f};
  float4 rA[2][4];
  uint4 rBh[2], rBl[2];
  #pragma unroll
  for (int i = 0; i < 4; ++i) rA[0][i] = *(const float4*)(ap + i * 16);
  rBh[0] = *(const uint4*)bhsrc;
  rBl[0] = *(const uint4*)blsrc;
  #pragma unroll
  for (int c = 0; c < NCH; ++c) {
    const int cur = c & 1, nxt = cur ^ 1;
    if (c + 1 < NCH) {          // issue next chunk's loads before touching cur
      #pragma unroll
      for (int i = 0; i < 4; ++i)
        rA[nxt][i] = *(const float4*)(ap + (c + 1) * KC + i * 16);
      rBh[nxt] = *(const uint4*)(bhsrc + (c + 1) * KC);
      rBl[nxt] = *(const uint4*)(blsrc + (c + 1) * KC);
    }
    if (c) __syncthreads();     // WAR: all waves done reading LDS of chunk c-1
    #pragma unroll
    for (int i = 0; i < 4; ++i) {
      float4 v = rA[cur][i];
      ushort4 hh, ll;
      hh.x = bf16_rne(v.x); ll.x = bf16_rne(v.x - bf16_f(hh.x));
      hh.y = bf16_rne(v.y); ll.y = bf16_rne(v.y - bf16_f(hh.y));
      hh.z = bf16_rne(v.z); ll.z = bf16_rne(v.z - bf16_f(hh.z));
      hh.w = bf16_rne(v.w); ll.w = bf16_rne(v.w - bf16_f(hh.w));
      *(ushort4*)&ah[sr][i * 16 + skq * 4] = hh;
      *(ushort4*)&al[sr][i * 16 + skq * 4] = ll;
    }
    *(uint4*)&bh[shh][sseg * 8] = rBh[cur];
    *(uint4*)&bl[shh][sseg * 8] = rBl[cur];
    __syncthreads();            // RAW: LDS staged
    const int arow = wave * 16 + m;
    #pragma unroll
    for (int ks = 0; ks < 2; ++ks) {
      v8s Ah  = *(const v8s*)&ah[arow][ks * 32 + quad * 8];
      v8s Al  = *(const v8s*)&al[arow][ks * 32 + quad * 8];
      v8s Bh0 = *(const v8s*)&bh[m][ks * 32 + quad * 8];
      v8s Bh1 = *(const v8s*)&bh[16 + m][ks * 32 + quad * 8];
      v8s Bl0 = *(const v8s*)&bl[m][ks * 32 + quad * 8];
      v8s Bl1 = *(const v8s*)&bl[16 + m][ks * 32 + quad * 8];
      acc0 = __builtin_amdgcn_mfma_f32_16x16x32_bf16(Ah, Bh0, acc0, 0, 0, 0);
      acc1 = __builtin_amdgcn_mfma_f32_16x16x32_bf16(Ah, Bh1, acc1, 0, 0, 0);
      acc0 = __builtin_amdgcn_mfma_f32_16x16x32_bf16(Al, Bh0, acc0, 0, 0, 0);
      acc1 = __builtin_amdgcn_mfma_f32_16x16x32_bf16(Al, Bh1, acc1, 0, 0, 0);
      acc0 = __builtin_amdgcn_mfma_f32_16x16x32_bf16(Ah, Bl0, acc0, 0, 0, 0);
      acc1 = __builtin_amdgcn_mfma_f32_16x16x32_bf16(Ah, Bl1, acc1, 0, 0, 0);
    }
  }
  // epilogue: D col = lane&15, row = quad*4 + reg
  float part[4];
  #pragma unroll
  for (int reg = 0; reg < 4; ++reg) {
    int row = row0 + wave * 16 + quad * 4 + reg;
    size_t o0 = ((size_t)b * NROW + row) * H + m;
    size_t o1 = o0 + 16;
    float v0 = fmaxf(acc0[reg] + g[o0], 0.f);
    float v1 = fmaxf(acc1[reg] + g[o1], 0.f);
    out[o0] = v0;
    out[o1] = v1;
    if (yout) part[reg] = v0 * psu[m] + v1 * psu[m + 16];
  }
  if (yout) {
    #pragma unroll
    for (int reg = 0; reg < 4; ++reg)
      #pragma unroll
      for (int off = 1; off < 16; off <<= 1)
        part[reg] += __shfl_xor(part[reg], off, 16);
    if (m < 4)
      yout[(size_t)b * NROW + row0 + wave * 16 + quad * 4 + m] = part[m];
  }
}

// ---------------- top-k over precomputed scores -> {local idx, gate, global idx} ----------------
template<int NN, int K>
__global__ __launch_bounds__(256) void k_topk(
    const float* __restrict__ y, const int* __restrict__ prev_idx,
    int* __restrict__ lidx, float* __restrict__ gate, int* __restrict__ out_idx) {
  __shared__ float ys[NN];
  __shared__ int is[NN];
  const int tid = threadIdx.x;
  const int b = blockIdx.x;
  for (int i = tid; i < NN; i += 256) {
    ys[i] = y[(size_t)b * NN + i];
    is[i] = i;
  }
  for (int k = 2; k <= NN; k <<= 1) {
    for (int j = k >> 1; j > 0; j >>= 1) {
      __syncthreads();
      for (int i = tid; i < NN; i += 256) {
        int ixj = i ^ j;
        if (ixj > i) {
          float v0 = ys[i], v1 = ys[ixj];
          int i0 = is[i], i1 = is[ixj];
          bool pre = (v1 > v0) || (v1 == v0 && i1 < i0);
          bool doswap = ((i & k) == 0) ? pre : !pre;
          if (doswap) { ys[i] = v1; ys[ixj] = v0; is[i] = i1; is[ixj] = i0; }
        }
      }
    }
  }
  for (int k = 2; k <= K; k <<= 1) {
    for (int j = k >> 1; j > 0; j >>= 1) {
      __syncthreads();
      for (int i = tid; i < K; i += 256) {
        int ixj = i ^ j;
        if (ixj > i && ixj < K) {
          float v0 = ys[i], v1 = ys[ixj];
          int i0 = is[i], i1 = is[ixj];
          bool pre = (i1 < i0);
          bool doswap = ((i & k) == 0) ? pre : !pre;
          if (doswap) { ys[i] = v1; ys[ixj] = v0; is[i] = i1; is[ixj] = i0; }
        }
      }
    }
  }
  __syncthreads();
  for (int t = tid; t < K; t += 256) {
    lidx[(size_t)b * K + t] = is[t];
    gate[(size_t)b * K + t] = 1.f / (1.f + expf(-ys[t]));
    out_idx[(size_t)b * K + t] = prev_idx ? prev_idx[(size_t)b * NN + is[t]] : is[t];
  }
}

// ---------------- mean over nodes -> dense -> softmax ----------------
__global__ __launch_bounds__(128) void k_head(
    const float* __restrict__ xl3, const float* __restrict__ wd,
    const float* __restrict__ bd, float* __restrict__ out) {
  __shared__ float part[4][H];
  __shared__ float pooled[H];
  __shared__ float wds[H * NC];
  __shared__ float logits[NC];
  const int tid = threadIdx.x;
  const int b = blockIdx.x;
  for (int i = tid; i < H * NC; i += 128) wds[i] = wd[i];
  const int f = tid & 31, nq = tid >> 5;
  float s = 0.f;
  for (int n = nq * 32; n < nq * 32 + 32; ++n)
    s += xl3[((size_t)b * 128 + n) * H + f];
  part[nq][f] = s;
  __syncthreads();
  if (tid < H)
    pooled[tid] = (part[0][tid] + part[1][tid] + part[2][tid] + part[3][tid]) * (1.f / 128.f);
  __syncthreads();
  if (tid < NC) {
    float acc = bd[tid];
    for (int i = 0; i < H; ++i) acc += pooled[i] * wds[i * NC + tid];
    logits[tid] = acc;
  }
  __syncthreads();
  if (tid == 0) {
    float mx = logits[0];
    for (int i = 1; i < NC; ++i) mx = fmaxf(mx, logits[i]);
    float e[NC], se = 0.f;
    for (int i = 0; i < NC; ++i) { e[i] = expf(logits[i] - mx); se += e[i]; }
    float inv = 1.f / se;
    for (int i = 0; i < NC; ++i) out[(size_t)b * NC + i] = e[i] * inv;
  }
}

extern "C" void kernel_launch(void* const* d_in, const int* in_sizes, int n_in,
                              void* d_out, int out_size, void* d_ws, size_t ws_size,
                              hipStream_t stream) {
  (void)in_sizes; (void)n_in; (void)out_size; (void)ws_size;
  const float* x    = (const float*)d_in[0];
  const float* a    = (const float*)d_in[1];
  const float* w1_1 = (const float*)d_in[2];
  const float* w2_1 = (const float*)d_in[3];
  const float* b1   = (const float*)d_in[4];
  const float* w1_2 = (const float*)d_in[5];
  const float* w2_2 = (const float*)d_in[6];
  const float* b2   = (const float*)d_in[7];
  const float* w1_3 = (const float*)d_in[8];
  const float* w2_3 = (const float*)d_in[9];
  const float* b3   = (const float*)d_in[10];
  const float* pp   = (const float*)d_in[11];
  const float* wd   = (const float*)d_in[12];
  const float* bd   = (const float*)d_in[13];
  float* out = (float*)d_out;

  char* w = (char*)d_ws;
  auto take = [&](size_t bytes) { char* r = w; w += (bytes + 255) & ~(size_t)255; return r; };
  ushort* hTh = (ushort*)take((size_t)B * H * N0 * 2);
  ushort* hTl = (ushort*)take((size_t)B * H * N0 * 2);
  float*  g1  = (float*) take((size_t)B * N0 * H * 4);
  float*  xl1 = (float*) take((size_t)B * N0 * H * 4);
  float*  y1  = (float*) take((size_t)B * N0 * 4);
  int*    id1 = (int*)   take((size_t)B * 256 * 4);
  int*    li1 = (int*)   take((size_t)B * 256 * 4);
  float*  gt1 = (float*) take((size_t)B * 256 * 4);
  float*  g2  = (float*) take((size_t)B * 256 * H * 4);
  float*  xl2 = (float*) take((size_t)B * 256 * H * 4);
  float*  y2  = (float*) take((size_t)B * 256 * 4);
  int*    id2 = (int*)   take((size_t)B * 128 * 4);
  int*    li2 = (int*)   take((size_t)B * 128 * 4);
  float*  gt2 = (float*) take((size_t)B * 128 * 4);
  float*  g3  = (float*) take((size_t)B * 128 * H * 4);
  float*  xl3 = (float*) take((size_t)B * 128 * H * 4);

  // Layer 1
  k_xw1<F0, 2><<<dim3(B * N0 / 64), dim3(256), 0, stream>>>(x, w1_1, w2_1, b1, hTh, hTl, g1);
  k_ammx<512><<<dim3(B, 8), dim3(256), 0, stream>>>(a, nullptr, hTh, hTl, g1, pp, xl1, y1);
  // Pool 1
  k_topk<512, 256><<<dim3(B), dim3(256), 0, stream>>>(y1, nullptr, li1, gt1, id1);
  // Layer 2 (xw + transpose fused; h2 buffer and 2 launches eliminated)
  k_xwg2<512, 256><<<dim3(B), dim3(256), 0, stream>>>(xl1, li1, gt1, id1, w1_2, w2_2, b2, g2, hTh, hTl);
  k_ammx<256><<<dim3(B, 4), dim3(256), 0, stream>>>(a, id1, hTh, hTl, g2, pp, xl2, y2);
  // Pool 2
  k_topk<256, 128><<<dim3(B), dim3(256), 0, stream>>>(y2, id1, li2, gt2, id2);
  // Layer 3
  k_xwg2<256, 128><<<dim3(B), dim3(256), 0, stream>>>(xl2, li2, gt2, id2, w1_3, w2_3, b3, g3, hTh, hTl);
  k_ammx<128><<<dim3(B, 2), dim3(256), 0, stream>>>(a, id2, hTh, hTl, g3, nullptr, xl3, nullptr);
  // Head
  k_head<<<dim3(B), dim3(128), 0, stream>>>(xl3, wd, bd, out);
}

// Round 3
// 580.982 us; speedup vs baseline: 1.0823x; 1.0823x over previous
//
#include <hip/hip_runtime.h>
#include <cmath>

#define B 256
#define N0 512
#define F0 128
#define H 32
#define NC 16

typedef short v8s __attribute__((ext_vector_type(8)));
typedef float v4f __attribute__((ext_vector_type(4)));
typedef unsigned short v8u __attribute__((ext_vector_type(8)));

__device__ inline ushort bf16_rne(float f) {
  unsigned u = __float_as_uint(f);
  unsigned r = (u + 0x7FFF + ((u >> 16) & 1)) >> 16;
  return (ushort)r;
}
__device__ inline float bf16_f(ushort s) { return __uint_as_float((unsigned)s << 16); }

// ---------------- Layer-1: x@w1 -> hT (bf16 split, transposed, fused); x@w2+b -> g ----------------
template<int F, int RPT>
__global__ __launch_bounds__(256) void k_xw1(
    const float* __restrict__ x, const float* __restrict__ w1,
    const float* __restrict__ w2, const float* __restrict__ bias,
    ushort* __restrict__ hTh, ushort* __restrict__ hTl, float* __restrict__ g) {
  __shared__ float w1t[H][F + 4];
  __shared__ float w2t[H][F + 4];
  __shared__ float bs[H];
  __shared__ __align__(16) ushort thi[H][72];
  __shared__ __align__(16) ushort tlo[H][72];
  const int tid = threadIdx.x;
  for (int i = tid; i < F * H; i += 256) {
    int f = i >> 5, hc = i & 31;
    w1t[hc][f] = w1[i];
    w2t[hc][f] = w2[i];
  }
  if (tid < H) bs[tid] = bias[tid];
  __syncthreads();
  const int hq = tid & 7;
  const int rq = tid >> 3;
  const size_t row0 = (size_t)blockIdx.x * (32 * RPT) + (size_t)rq * RPT;
  const float* xb = x + row0 * F;
  float acc1[RPT][4];
  float acc2[RPT][4];
  #pragma unroll
  for (int r = 0; r < RPT; ++r)
    for (int c = 0; c < 4; ++c) { acc1[r][c] = 0.f; acc2[r][c] = 0.f; }
  for (int f0 = 0; f0 < F; f0 += 4) {
    float4 w1v[4], w2v[4];
    #pragma unroll
    for (int hh = 0; hh < 4; ++hh) {
      w1v[hh] = *(const float4*)&w1t[hq * 4 + hh][f0];
      w2v[hh] = *(const float4*)&w2t[hq * 4 + hh][f0];
    }
    #pragma unroll
    for (int r = 0; r < RPT; ++r) {
      float4 xv = *(const float4*)(xb + (size_t)r * F + f0);
      #pragma unroll
      for (int hh = 0; hh < 4; ++hh) {
        acc1[r][hh] += xv.x * w1v[hh].x + xv.y * w1v[hh].y + xv.z * w1v[hh].z + xv.w * w1v[hh].w;
        acc2[r][hh] += xv.x * w2v[hh].x + xv.y * w2v[hh].y + xv.z * w2v[hh].z + xv.w * w2v[hh].w;
      }
    }
  }
  #pragma unroll
  for (int r = 0; r < RPT; ++r) {
    size_t o = (row0 + r) * H + hq * 4;
    *(float4*)(g + o) = make_float4(acc2[r][0] + bs[hq * 4 + 0], acc2[r][1] + bs[hq * 4 + 1],
                                    acc2[r][2] + bs[hq * 4 + 2], acc2[r][3] + bs[hq * 4 + 3]);
    #pragma unroll
    for (int c = 0; c < 4; ++c) {
      float v = acc1[r][c];
      ushort hi = bf16_rne(v);
      thi[hq * 4 + c][rq * RPT + r] = hi;
      tlo[hq * 4 + c][rq * RPT + r] = bf16_rne(v - bf16_f(hi));
    }
  }
  __syncthreads();
  const int b = blockIdx.x >> 3;
  const int j0 = (blockIdx.x & 7) * 64;
  const int hrow = tid >> 3, seg = tid & 7;
  size_t o = ((size_t)b * H + hrow) * N0 + j0 + seg * 8;
  *(uint4*)&hTh[o] = *(const uint4*)&thi[hrow][seg * 8];
  *(uint4*)&hTl[o] = *(const uint4*)&tlo[hrow][seg * 8];
}

// ---------------- Layers 2/3: gathered+gated x@w1 -> h ; x@w2+b -> g ----------------
template<int NPREV, int K, int RPT>
__global__ __launch_bounds__(256) void k_xwg(
    const float* __restrict__ xsrc, const int* __restrict__ lidx,
    const float* __restrict__ gate,
    const float* __restrict__ w1, const float* __restrict__ w2,
    const float* __restrict__ bias,
    float* __restrict__ h, float* __restrict__ g) {
  constexpr int F = H;
  __shared__ float w1t[H][F + 4];
  __shared__ float w2t[H][F + 4];
  __shared__ float bs[H];
  const int tid = threadIdx.x;
  for (int i = tid; i < F * H; i += 256) {
    int f = i >> 5, hc = i & 31;
    w1t[hc][f] = w1[i];
    w2t[hc][f] = w2[i];
  }
  if (tid < H) bs[tid] = bias[tid];
  __syncthreads();
  const int hq = tid & 7;
  const int rq = tid >> 3;
  const int row0 = blockIdx.x * (32 * RPT) + rq * RPT;   // flat over B*K
  const int b = row0 / K;
  const float* xg0 = xsrc + (size_t)b * NPREV * H;
  int li[RPT];
  float gt[RPT];
  #pragma unroll
  for (int r = 0; r < RPT; ++r) { li[r] = lidx[row0 + r]; gt[r] = gate[row0 + r]; }
  float acc1[RPT][4];
  float acc2[RPT][4];
  #pragma unroll
  for (int r = 0; r < RPT; ++r)
    for (int c = 0; c < 4; ++c) { acc1[r][c] = 0.f; acc2[r][c] = 0.f; }
  for (int f0 = 0; f0 < F; f0 += 4) {
    float4 w1v[4], w2v[4];
    #pragma unroll
    for (int hh = 0; hh < 4; ++hh) {
      w1v[hh] = *(const float4*)&w1t[hq * 4 + hh][f0];
      w2v[hh] = *(const float4*)&w2t[hq * 4 + hh][f0];
    }
    #pragma unroll
    for (int r = 0; r < RPT; ++r) {
      float4 xv = *(const float4*)(xg0 + (size_t)li[r] * H + f0);
      #pragma unroll
      for (int hh = 0; hh < 4; ++hh) {
        acc1[r][hh] += xv.x * w1v[hh].x + xv.y * w1v[hh].y + xv.z * w1v[hh].z + xv.w * w1v[hh].w;
        acc2[r][hh] += xv.x * w2v[hh].x + xv.y * w2v[hh].y + xv.z * w2v[hh].z + xv.w * w2v[hh].w;
      }
    }
  }
  #pragma unroll
  for (int r = 0; r < RPT; ++r) {
    size_t o = ((size_t)row0 + r) * H + hq * 4;
    *(float4*)(h + o) = make_float4(acc1[r][0] * gt[r], acc1[r][1] * gt[r],
                                    acc1[r][2] * gt[r], acc1[r][3] * gt[r]);
    *(float4*)(g + o) = make_float4(acc2[r][0] * gt[r] + bs[hq * 4 + 0],
                                    acc2[r][1] * gt[r] + bs[hq * 4 + 1],
                                    acc2[r][2] * gt[r] + bs[hq * 4 + 2],
                                    acc2[r][3] * gt[r] + bs[hq * 4 + 3]);
  }
}

// ------------- dense inverse-map transpose+split: h[B][K][32], global idx -> hT[32][N0] -------------
template<int K>
__global__ __launch_bounds__(512) void k_trans_inv(
    const float* __restrict__ hd, const int* __restrict__ idx,
    ushort* __restrict__ hTh, ushort* __restrict__ hTl) {
  __shared__ float hs[K][33];
  __shared__ int inv[N0];
  const int tid = threadIdx.x;
  const int b = blockIdx.x;
  for (int j = tid; j < N0; j += 512) inv[j] = -1;
  __syncthreads();
  for (int k = tid; k < K; k += 512) inv[idx[(size_t)b * K + k]] = k;
  for (int t = tid; t < K * 8; t += 512) {
    int r = t >> 3, c4 = t & 7;
    float4 v = *(const float4*)(hd + (((size_t)b * K) + r) * H + c4 * 4);
    hs[r][c4 * 4 + 0] = v.x;
    hs[r][c4 * 4 + 1] = v.y;
    hs[r][c4 * 4 + 2] = v.z;
    hs[r][c4 * 4 + 3] = v.w;
  }
  __syncthreads();
  for (int t = tid; t < H * 64; t += 512) {
    int hr = t >> 6, seg = t & 63;
    v8u hv, lv;
    #pragma unroll
    for (int i = 0; i < 8; ++i) {
      int k = inv[seg * 8 + i];
      float v = (k >= 0) ? hs[k][hr] : 0.f;
      ushort hi = bf16_rne(v);
      hv[i] = hi;
      lv[i] = bf16_rne(v - bf16_f(hi));
    }
    size_t o = ((size_t)b * H + hr) * N0 + seg * 8;
    *(v8u*)&hTh[o] = hv;
    *(v8u*)&hTl[o] = lv;
  }
}

// ---------------- MFMA amm: out = relu(A[rid,:] @ h + g), split-bf16, K=512 ----------------
// KC=32 (R1-proven layout). Depth-1 rotating register prefetch: loads for chunk c+1
// issue before the WAR barrier of chunk c, staying in flight across convert+MFMA.
template<int NROW>
__global__ __launch_bounds__(256) void k_ammx(
    const float* __restrict__ a0, const int* __restrict__ rid,
    const ushort* __restrict__ hTh, const ushort* __restrict__ hTl,
    const float* __restrict__ g, const float* __restrict__ p,
    float* __restrict__ out, float* __restrict__ yout) {
  constexpr int RB = 64;
  constexpr int KC = 32;
  constexpr int ASP = KC + 8;   // 40: keeps b128 frag reads 16B-aligned
  __shared__ ushort ah[RB][ASP];
  __shared__ ushort al[RB][ASP];
  __shared__ ushort bh[H][ASP];
  __shared__ ushort bl[H][ASP];
  __shared__ int rowid[RB];
  __shared__ float psu[H];
  __shared__ float pns_s;
  const int tid = threadIdx.x;
  const int b = blockIdx.x;
  const int row0 = blockIdx.y * RB;
  if (tid < RB) rowid[tid] = rid ? rid[(size_t)b * NROW + row0 + tid] : row0 + tid;
  if (yout && tid == 0) {
    float s = 0.f;
    for (int i = 0; i < H; ++i) s += p[i] * p[i];
    pns_s = 1.f / sqrtf(s);
  }
  __syncthreads();
  if (yout && tid < H) psu[tid] = p[tid] * pns_s;  // consumed after in-loop barriers
  const int wave = tid >> 6, lane = tid & 63;
  const int m = lane & 15, quad = lane >> 4;
  const int sr = tid >> 2, skq = tid & 3;     // A staging: row, col-group
  const int shh = tid >> 3, sseg = tid & 7;   // B staging: h-row, seg
  const float* ap = a0 + (size_t)b * N0 * N0 + (size_t)rowid[sr] * N0 + skq * 4;
  const ushort* bhsrc = hTh + ((size_t)b * H + shh) * N0 + sseg * 4;
  const ushort* blsrc = hTl + ((size_t)b * H + shh) * N0 + sseg * 4;
  v4f acc0 = {0.f, 0.f, 0.f, 0.f};
  v4f acc1 = {0.f, 0.f, 0.f, 0.f};
  // prologue: chunk 0 into registers
  float4 pA0 = *(const float4*)(ap);
  float4 pA1 = *(const float4*)(ap + 16);
  ushort4 pBh = *(const ushort4*)(bhsrc);
  ushort4 pBl = *(const ushort4*)(blsrc);
  for (int k0 = 0; k0 < N0; k0 += KC) {
    // issue next chunk's loads before this chunk's barriers/compute
    float4 nA0, nA1;
    ushort4 nBh, nBl;
    if (k0 + KC < N0) {
      nA0 = *(const float4*)(ap + k0 + KC);
      nA1 = *(const float4*)(ap + k0 + KC + 16);
      nBh = *(const ushort4*)(bhsrc + k0 + KC);
      nBl = *(const ushort4*)(blsrc + k0 + KC);
    }
    if (k0) __syncthreads();   // WAR: all waves done reading LDS of previous chunk
    // stage A: convert prefetched fp32 -> bf16 hi/lo
    {
      ushort4 h0, l0, h1, l1;
      h0.x = bf16_rne(pA0.x); l0.x = bf16_rne(pA0.x - bf16_f(h0.x));
      h0.y = bf16_rne(pA0.y); l0.y = bf16_rne(pA0.y - bf16_f(h0.y));
      h0.z = bf16_rne(pA0.z); l0.z = bf16_rne(pA0.z - bf16_f(h0.z));
      h0.w = bf16_rne(pA0.w); l0.w = bf16_rne(pA0.w - bf16_f(h0.w));
      h1.x = bf16_rne(pA1.x); l1.x = bf16_rne(pA1.x - bf16_f(h1.x));
      h1.y = bf16_rne(pA1.y); l1.y = bf16_rne(pA1.y - bf16_f(h1.y));
      h1.z = bf16_rne(pA1.z); l1.z = bf16_rne(pA1.z - bf16_f(h1.z));
      h1.w = bf16_rne(pA1.w); l1.w = bf16_rne(pA1.w - bf16_f(h1.w));
      *(ushort4*)&ah[sr][skq * 4] = h0;      *(ushort4*)&al[sr][skq * 4] = l0;
      *(ushort4*)&ah[sr][skq * 4 + 16] = h1; *(ushort4*)&al[sr][skq * 4 + 16] = l1;
    }
    // stage B: prefetched bf16 hi/lo
    *(ushort4*)&bh[shh][sseg * 4] = pBh;
    *(ushort4*)&bl[shh][sseg * 4] = pBl;
    __syncthreads();           // RAW: LDS staged
    const int arow = wave * 16 + m;
    v8s Ah = *(const v8s*)&ah[arow][quad * 8];
    v8s Al = *(const v8s*)&al[arow][quad * 8];
    v8s Bh0 = *(const v8s*)&bh[m][quad * 8];
    v8s Bh1 = *(const v8s*)&bh[16 + m][quad * 8];
    v8s Bl0 = *(const v8s*)&bl[m][quad * 8];
    v8s Bl1 = *(const v8s*)&bl[16 + m][quad * 8];
    acc0 = __builtin_amdgcn_mfma_f32_16x16x32_bf16(Ah, Bh0, acc0, 0, 0, 0);
    acc1 = __builtin_amdgcn_mfma_f32_16x16x32_bf16(Ah, Bh1, acc1, 0, 0, 0);
    acc0 = __builtin_amdgcn_mfma_f32_16x16x32_bf16(Al, Bh0, acc0, 0, 0, 0);
    acc1 = __builtin_amdgcn_mfma_f32_16x16x32_bf16(Al, Bh1, acc1, 0, 0, 0);
    acc0 = __builtin_amdgcn_mfma_f32_16x16x32_bf16(Ah, Bl0, acc0, 0, 0, 0);
    acc1 = __builtin_amdgcn_mfma_f32_16x16x32_bf16(Ah, Bl1, acc1, 0, 0, 0);
    // rotate prefetch buffers
    pA0 = nA0; pA1 = nA1; pBh = nBh; pBl = nBl;
  }
  // epilogue: D col = lane&15, row = quad*4 + reg
  float part[4];
  #pragma unroll
  for (int reg = 0; reg < 4; ++reg) {
    int row = row0 + wave * 16 + quad * 4 + reg;
    size_t o0 = ((size_t)b * NROW + row) * H + m;
    size_t o1 = o0 + 16;
    float v0 = fmaxf(acc0[reg] + g[o0], 0.f);
    float v1 = fmaxf(acc1[reg] + g[o1], 0.f);
    out[o0] = v0;
    out[o1] = v1;
    if (yout) part[reg] = v0 * psu[m] + v1 * psu[m + 16];
  }
  if (yout) {
    #pragma unroll
    for (int reg = 0; reg < 4; ++reg)
      #pragma unroll
      for (int off = 1; off < 16; off <<= 1)
        part[reg] += __shfl_xor(part[reg], off, 16);
    if (m < 4)
      yout[(size_t)b * NROW + row0 + wave * 16 + quad * 4 + m] = part[m];
  }
}

// ---------------- top-k over precomputed scores -> {local idx, gate, global idx} ----------------
template<int NN, int K>
__global__ __launch_bounds__(256) void k_topk(
    const float* __restrict__ y, const int* __restrict__ prev_idx,
    int* __restrict__ lidx, float* __restrict__ gate, int* __restrict__ out_idx) {
  __shared__ float ys[NN];
  __shared__ int is[NN];
  const int tid = threadIdx.x;
  const int b = blockIdx.x;
  for (int i = tid; i < NN; i += 256) {
    ys[i] = y[(size_t)b * NN + i];
    is[i] = i;
  }
  for (int k = 2; k <= NN; k <<= 1) {
    for (int j = k >> 1; j > 0; j >>= 1) {
      __syncthreads();
      for (int i = tid; i < NN; i += 256) {
        int ixj = i ^ j;
        if (ixj > i) {
          float v0 = ys[i], v1 = ys[ixj];
          int i0 = is[i], i1 = is[ixj];
          bool pre = (v1 > v0) || (v1 == v0 && i1 < i0);
          bool doswap = ((i & k) == 0) ? pre : !pre;
          if (doswap) { ys[i] = v1; ys[ixj] = v0; is[i] = i1; is[ixj] = i0; }
        }
      }
    }
  }
  for (int k = 2; k <= K; k <<= 1) {
    for (int j = k >> 1; j > 0; j >>= 1) {
      __syncthreads();
      for (int i = tid; i < K; i += 256) {
        int ixj = i ^ j;
        if (ixj > i && ixj < K) {
          float v0 = ys[i], v1 = ys[ixj];
          int i0 = is[i], i1 = is[ixj];
          bool pre = (i1 < i0);
          bool doswap = ((i & k) == 0) ? pre : !pre;
          if (doswap) { ys[i] = v1; ys[ixj] = v0; is[i] = i1; is[ixj] = i0; }
        }
      }
    }
  }
  __syncthreads();
  for (int t = tid; t < K; t += 256) {
    lidx[(size_t)b * K + t] = is[t];
    gate[(size_t)b * K + t] = 1.f / (1.f + expf(-ys[t]));
    out_idx[(size_t)b * K + t] = prev_idx ? prev_idx[(size_t)b * NN + is[t]] : is[t];
  }
}

// ---------------- mean over nodes -> dense -> softmax ----------------
__global__ __launch_bounds__(128) void k_head(
    const float* __restrict__ xl3, const float* __restrict__ wd,
    const float* __restrict__ bd, float* __restrict__ out) {
  __shared__ float part[4][H];
  __shared__ float pooled[H];
  __shared__ float wds[H * NC];
  __shared__ float logits[NC];
  const int tid = threadIdx.x;
  const int b = blockIdx.x;
  for (int i = tid; i < H * NC; i += 128) wds[i] = wd[i];
  const int f = tid & 31, nq = tid >> 5;
  float s = 0.f;
  for (int n = nq * 32; n < nq * 32 + 32; ++n)
    s += xl3[((size_t)b * 128 + n) * H + f];
  part[nq][f] = s;
  __syncthreads();
  if (tid < H)
    pooled[tid] = (part[0][tid] + part[1][tid] + part[2][tid] + part[3][tid]) * (1.f / 128.f);
  __syncthreads();
  if (tid < NC) {
    float acc = bd[tid];
    for (int i = 0; i < H; ++i) acc += pooled[i] * wds[i * NC + tid];
    logits[tid] = acc;
  }
  __syncthreads();
  if (tid == 0) {
    float mx = logits[0];
    for (int i = 1; i < NC; ++i) mx = fmaxf(mx, logits[i]);
    float e[NC], se = 0.f;
    for (int i = 0; i < NC; ++i) { e[i] = expf(logits[i] - mx); se += e[i]; }
    float inv = 1.f / se;
    for (int i = 0; i < NC; ++i) out[(size_t)b * NC + i] = e[i] * inv;
  }
}

extern "C" void kernel_launch(void* const* d_in, const int* in_sizes, int n_in,
                              void* d_out, int out_size, void* d_ws, size_t ws_size,
                              hipStream_t stream) {
  (void)in_sizes; (void)n_in; (void)out_size; (void)ws_size;
  const float* x    = (const float*)d_in[0];
  const float* a    = (const float*)d_in[1];
  const float* w1_1 = (const float*)d_in[2];
  const float* w2_1 = (const float*)d_in[3];
  const float* b1   = (const float*)d_in[4];
  const float* w1_2 = (const float*)d_in[5];
  const float* w2_2 = (const float*)d_in[6];
  const float* b2   = (const float*)d_in[7];
  const float* w1_3 = (const float*)d_in[8];
  const float* w2_3 = (const float*)d_in[9];
  const float* b3   = (const float*)d_in[10];
  const float* pp   = (const float*)d_in[11];
  const float* wd   = (const float*)d_in[12];
  const float* bd   = (const float*)d_in[13];
  float* out = (float*)d_out;

  char* w = (char*)d_ws;
  auto take = [&](size_t bytes) { char* r = w; w += (bytes + 255) & ~(size_t)255; return r; };
  ushort* hTh = (ushort*)take((size_t)B * H * N0 * 2);
  ushort* hTl = (ushort*)take((size_t)B * H * N0 * 2);
  float*  g1  = (float*) take((size_t)B * N0 * H * 4);
  float*  xl1 = (float*) take((size_t)B * N0 * H * 4);
  float*  y1  = (float*) take((size_t)B * N0 * 4);
  int*    id1 = (int*)   take((size_t)B * 256 * 4);
  int*    li1 = (int*)   take((size_t)B * 256 * 4);
  float*  gt1 = (float*) take((size_t)B * 256 * 4);
  float*  h2  = (float*) take((size_t)B * 256 * H * 4);
  float*  g2  = (float*) take((size_t)B * 256 * H * 4);
  float*  xl2 = (float*) take((size_t)B * 256 * H * 4);
  float*  y2  = (float*) take((size_t)B * 256 * 4);
  int*    id2 = (int*)   take((size_t)B * 128 * 4);
  int*    li2 = (int*)   take((size_t)B * 128 * 4);
  float*  gt2 = (float*) take((size_t)B * 128 * 4);
  float*  h3  = (float*) take((size_t)B * 128 * H * 4);
  float*  g3  = (float*) take((size_t)B * 128 * H * 4);
  float*  xl3 = (float*) take((size_t)B * 128 * H * 4);

  // Layer 1
  k_xw1<F0, 2><<<dim3(B * N0 / 64), dim3(256), 0, stream>>>(x, w1_1, w2_1, b1, hTh, hTl, g1);
  k_ammx<512><<<dim3(B, 8), dim3(256), 0, stream>>>(a, nullptr, hTh, hTl, g1, pp, xl1, y1);
  // Pool 1
  k_topk<512, 256><<<dim3(B), dim3(256), 0, stream>>>(y1, nullptr, li1, gt1, id1);
  // Layer 2
  k_xwg<512, 256, 4><<<dim3(B * 256 / 128), dim3(256), 0, stream>>>(xl1, li1, gt1, w1_2, w2_2, b2, h2, g2);
  k_trans_inv<256><<<dim3(B), dim3(512), 0, stream>>>(h2, id1, hTh, hTl);
  k_ammx<256><<<dim3(B, 4), dim3(256), 0, stream>>>(a, id1, hTh, hTl, g2, pp, xl2, y2);
  // Pool 2
  k_topk<256, 128><<<dim3(B), dim3(256), 0, stream>>>(y2, id1, li2, gt2, id2);
  // Layer 3
  k_xwg<256, 128, 4><<<dim3(B * 128 / 128), dim3(256), 0, stream>>>(xl2, li2, gt2, w1_3, w2_3, b3, h3, g3);
  k_trans_inv<128><<<dim3(B), dim3(512), 0, stream>>>(h3, id2, hTh, hTl);
  k_ammx<128><<<dim3(B, 2), dim3(256), 0, stream>>>(a, id2, hTh, hTl, g3, nullptr, xl3, nullptr);
  // Head
  k_head<<<dim3(B), dim3(128), 0, stream>>>(xl3, wd, bd, out);
}